// Round 1
// baseline (604.747 us; speedup 1.0000x reference)
//
#include <hip/hip_runtime.h>
#include <math.h>

// Problem constants
#define NB 64       // batch
#define NI 2048     // input capsules
#define NK 32       // output capsules
#define ND 16       // in_dim = out_dim

// ---------------------------------------------------------------------------
// Fused routing pass.
//   PASS=0: s0[b,k,o] += sum_d x[b,i,d]*W[i,k,d,o]        (uniform coupling)
//   PASS=1: u = u_hat[b,i,k,:]; lg = <u, Vin[b,k,:]>; c = softmax_k(lg);
//           s[b,k,o] += c * u[o]
// Thread map (256 thr): kk = t&31 (capsule k), oh = (t>>5)&1 (o-half),
//                       bq4 = t>>6 (wave id = b-quad). Block covers 16 b, IC i.
// ---------------------------------------------------------------------------
template<int PASS>
__global__ __launch_bounds__(256, 2)
void caps_pass(const float* __restrict__ X,    // [64][2048][16]
               const float* __restrict__ Wg,   // [2048][32][16][16]
               const float* __restrict__ Vin,  // [64][32][16] (PASS=1) or null
               float* __restrict__ Sout)       // [64][32][16], atomically accumulated
{
    constexpr int IC = 16;                  // i's per block
    __shared__ float Ws[8192];              // W[i], XOR-swizzled [k][d][o]
    __shared__ float Xs[16 * 20];           // x transposed [d][b], padded stride 20

    const int t   = threadIdx.x;
    const int kk  = t & 31;
    const int oh  = (t >> 5) & 1;           // o-half: o in [oh*8, oh*8+8)
    const int bq4 = t >> 6;                 // wave id, b-quad
    const int b0  = blockIdx.y * 16;
    const int i0  = blockIdx.x * IC;

    float s_acc[4][8];
#pragma unroll
    for (int bb = 0; bb < 4; ++bb)
#pragma unroll
        for (int o = 0; o < 8; ++o) s_acc[bb][o] = 0.f;

    // v fragments held in registers for the whole block (constant over i)
    float v_r[4][8];
    if constexpr (PASS) {
#pragma unroll
        for (int bb = 0; bb < 4; ++bb) {
            const float* vp = Vin + ((size_t)(b0 + bq4 * 4 + bb) * NK + kk) * 16 + oh * 8;
            float4 a = *(const float4*)(vp);
            float4 c = *(const float4*)(vp + 4);
            v_r[bb][0]=a.x; v_r[bb][1]=a.y; v_r[bb][2]=a.z; v_r[bb][3]=a.w;
            v_r[bb][4]=c.x; v_r[bb][5]=c.y; v_r[bb][6]=c.z; v_r[bb][7]=c.w;
        }
    }

    for (int ii = 0; ii < IC; ++ii) {
        const int i = i0 + ii;
        __syncthreads();   // previous iteration's LDS readers done

        // ---- stage W[i] (8192 floats) into LDS with XOR quad-swizzle ----
        {
            const float4* wsrc = (const float4*)(Wg + (size_t)i * 8192);
#pragma unroll
            for (int j = 0; j < 8; ++j) {
                float4 val = wsrc[t + j * 256];          // coalesced
                const int k   = (t >> 6) + 4 * j;        // wave-uniform
                const int rem = (t & 63) * 4;            // d*16+o within k-block
                const int idx = k * 256 + (rem ^ ((k & 7) << 2));
                *(float4*)(&Ws[idx]) = val;
            }
            // ---- stage x[b0..b0+15][i][:] transposed to [d][b] ----
            const int bb = t >> 4;     // 0..15
            const int d  = t & 15;
            Xs[d * 20 + bb] = X[(size_t)(b0 + bb) * (NI * ND) + (size_t)i * ND + d];
        }
        __syncthreads();

        // ---- compute u_hat fragments and accumulate ----
        float u[4][8];
        if constexpr (PASS) {
#pragma unroll
            for (int bb = 0; bb < 4; ++bb)
#pragma unroll
                for (int o = 0; o < 8; ++o) u[bb][o] = 0.f;
        }
#pragma unroll
        for (int d = 0; d < 16; ++d) {
            // x for this wave's 4 batches: single broadcast float4
            const float4 x4 = *(const float4*)(&Xs[d * 20 + bq4 * 4]);
            float wv[8];
#pragma unroll
            for (int qq = 0; qq < 2; ++qq) {
                const int q   = oh * 2 + qq;
                const int idx = kk * 256 + ((d * 16 + q * 4) ^ ((kk & 7) << 2));
                const float4 w4 = *(const float4*)(&Ws[idx]);
                wv[qq*4+0]=w4.x; wv[qq*4+1]=w4.y; wv[qq*4+2]=w4.z; wv[qq*4+3]=w4.w;
            }
            if constexpr (PASS) {
#pragma unroll
                for (int o = 0; o < 8; ++o) {
                    u[0][o] = fmaf(x4.x, wv[o], u[0][o]);
                    u[1][o] = fmaf(x4.y, wv[o], u[1][o]);
                    u[2][o] = fmaf(x4.z, wv[o], u[2][o]);
                    u[3][o] = fmaf(x4.w, wv[o], u[3][o]);
                }
            } else {
#pragma unroll
                for (int o = 0; o < 8; ++o) {
                    s_acc[0][o] = fmaf(x4.x, wv[o], s_acc[0][o]);
                    s_acc[1][o] = fmaf(x4.y, wv[o], s_acc[1][o]);
                    s_acc[2][o] = fmaf(x4.z, wv[o], s_acc[2][o]);
                    s_acc[3][o] = fmaf(x4.w, wv[o], s_acc[3][o]);
                }
            }
        }

        if constexpr (PASS) {
#pragma unroll
            for (int bb = 0; bb < 4; ++bb) {
                // logit over full o: own half + partner half (lane ^ 32 = other oh)
                float lg = 0.f;
#pragma unroll
                for (int o = 0; o < 8; ++o) lg = fmaf(u[bb][o], v_r[bb][o], lg);
                lg += __shfl_xor(lg, 32);
                // softmax over kk (32 lanes within each half)
                float m = lg;
#pragma unroll
                for (int mask = 16; mask >= 1; mask >>= 1)
                    m = fmaxf(m, __shfl_xor(m, mask));
                const float e = __expf(lg - m);
                float ssum = e;
#pragma unroll
                for (int mask = 16; mask >= 1; mask >>= 1)
                    ssum += __shfl_xor(ssum, mask);
                const float c = e / ssum;
#pragma unroll
                for (int o = 0; o < 8; ++o)
                    s_acc[bb][o] = fmaf(c, u[bb][o], s_acc[bb][o]);
            }
        }
    }

    // ---- accumulate block partials to global (disjoint per thread within block) ----
#pragma unroll
    for (int bb = 0; bb < 4; ++bb) {
        float* sp = Sout + ((size_t)(b0 + bq4 * 4 + bb) * NK + kk) * 16 + oh * 8;
#pragma unroll
        for (int o = 0; o < 8; ++o) atomicAdd(sp + o, s_acc[bb][o]);
    }
}

// ---------------------------------------------------------------------------
// v = squash(S*scale) (+ Vprev if given).  16 contiguous elems per (b,k) row;
// 16-lane shfl reduction (lane groups aligned since idx%16 == o).
// ---------------------------------------------------------------------------
__global__ __launch_bounds__(256)
void squash_kernel(const float* __restrict__ S, float scale,
                   const float* __restrict__ Vprev,
                   float* __restrict__ Vout)
{
    const int idx = blockIdx.x * 256 + threadIdx.x;   // 0..32767
    float val = S[idx] * scale;
    float sq = val * val;
#pragma unroll
    for (int mask = 8; mask >= 1; mask >>= 1) sq += __shfl_xor(sq, mask);
    const float sc = sqrtf(sq) / (1.0f + sq);
    float out = val * sc;
    if (Vprev) out += Vprev[idx];
    Vout[idx] = out;
}

extern "C" void kernel_launch(void* const* d_in, const int* in_sizes, int n_in,
                              void* d_out, int out_size, void* d_ws, size_t ws_size,
                              hipStream_t stream)
{
    const float* X  = (const float*)d_in[0];   // [64][2048][16]
    const float* Wg = (const float*)d_in[1];   // [2048][32][16][16]
    float* out = (float*)d_out;                // [64][32][16]

    float* ws  = (float*)d_ws;
    float* s0  = ws;            // 32768
    float* s1  = ws + 32768;
    float* s2  = ws + 65536;
    float* v0  = ws + 98304;
    float* v01 = ws + 131072;   // total 640 KB

    // zero the three accumulation buffers (graph-capturable)
    hipMemsetAsync(ws, 0, (size_t)3 * 32768 * sizeof(float), stream);

    const dim3 pgrid(NI / 16, 4);   // 128 i-chunks x 4 b-groups = 512 blocks
    const dim3 pblk(256);
    const dim3 qgrid(32768 / 256);  // 128 blocks

    // Pass A: s0 = sum_i u_hat  (coupling uniform; scale 1/32 applied in squash)
    caps_pass<0><<<pgrid, pblk, 0, stream>>>(X, Wg, nullptr, s0);
    squash_kernel<<<qgrid, pblk, 0, stream>>>(s0, 1.0f / 32.0f, nullptr, v0);

    // Pass B: logits = <u_hat, v0>; s1 = sum_i softmax_k * u_hat
    caps_pass<1><<<pgrid, pblk, 0, stream>>>(X, Wg, v0, s1);
    // v01 = v0 + squash(s1)  (b2 = <u_hat, v0+v1> since b starts at 0)
    squash_kernel<<<qgrid, pblk, 0, stream>>>(s1, 1.0f, v0, v01);

    // Pass C: logits = <u_hat, v01>; s2 = sum_i softmax_k * u_hat
    caps_pass<1><<<pgrid, pblk, 0, stream>>>(X, Wg, v01, s2);
    squash_kernel<<<qgrid, pblk, 0, stream>>>(s2, 1.0f, nullptr, out);
}